// Round 12
// baseline (135.929 us; speedup 1.0000x reference)
//
#include <hip/hip_runtime.h>

// Sinkhorn (dustbin-augmented), MFMA edition v12 = v9 loop + v11 epilogue +
// double-batch pipelining: each block processes TWO batches; batch k+1's
// scores are staged into esT DURING batch k's iteration loop via
// __builtin_amdgcn_global_load_lds (HBM->LDS direct, zero VGPR payload --
// the wave budget is exactly full at 64V+64A).
//
// Scaled exp-domain state (A = 2^{alpha*log2e}, Cs = 2^8/A):
//   EU_i  = 1/(sum_j es_ij*EV_j + A*evd)         es = 2^{s*log2e} (f16)
//   eud_s = Cs/(sum_j EV_j + evd)
//   EV_j  = 1/(sum_i es_ij*EU_i + A*eud_s)
//   evd'  = Cs/(sum_i EU_i + eud_s)
//   Z core = (log2 es + log2 EU + log2 EV)*ln2   (dustbins use alpha2)
//
// Staging pipeline (batch k loop, 20 iters): chunk c = 16 matrix rows (16 KB
// raw f32). Iter c (c<=15): issue 1 global_load_lds_dwordx4 per wave into
// rawbuf[wave's 1KB]. Iter c+1: vmcnt(0), each thread converts ITS OWN
// wave's region (float4 -> 4x exp2 -> 4x ds_write_b16 into swizzled esT).
// rawbuf regions are wave-private => no barrier needed; esT writes complete
// before batch k+1's gather via the loop's own barriers + the post-loop one.
//
// Fragment maps (proven v8..v11): wave w, lane l = l15 + 16g:
//   esA[s][j] = es[16w+l15][s*32+g*8+j]   (A operand, row strip)
//   esB[s][j] = es[s*32+g*8+j][16w+l15]   (B operand, col strip)
// C/D layout: col=lane&15, row=(lane>>4)*4+reg (HW-measured).

typedef _Float16 half8 __attribute__((ext_vector_type(8)));
typedef float floatx4 __attribute__((ext_vector_type(4)));

constexpr float L2E = 1.4426950408889634f;
constexpr float LN2 = 0.6931471805599453f;

__device__ __forceinline__ float flog2(float x) { return __builtin_amdgcn_logf(x); }
__device__ __forceinline__ float fexp2(float x) { return __builtin_amdgcn_exp2f(x); }

// 1/d via v_rcp_f32 + one Newton step (<=1 ulp, d>0)
__device__ __forceinline__ float rcp_nr(float d) {
    float r = __builtin_amdgcn_rcpf(d);
    return r * fmaf(-d, r, 2.0f);
}

template <int CTRL>
__device__ __forceinline__ float dpp_add(float x) {
    int y = __builtin_amdgcn_update_dpp(0, __builtin_bit_cast(int, x), CTRL, 0xF, 0xF, true);
    return x + __builtin_bit_cast(float, y);
}
__device__ __forceinline__ float reduce16(float x) {
    x = dpp_add<0xB1>(x);    // xor 1
    x = dpp_add<0x4E>(x);    // xor 2
    x = dpp_add<0x124>(x);   // row_ror:4
    x = dpp_add<0x128>(x);   // row_ror:8
    return x;
}
__device__ __forceinline__ float xor16_add(float x) {
    int y = __builtin_amdgcn_ds_swizzle(__builtin_bit_cast(int, x), 0x401F);
    return x + __builtin_bit_cast(float, y);
}

__global__ __launch_bounds__(1024)
__attribute__((amdgpu_waves_per_eu(4, 4)))
void sinkhorn_kernel(const float* __restrict__ scores,
                     const float* __restrict__ alpha_p,
                     const int* __restrict__ iters_p,
                     float* __restrict__ out, int B)
{
    const int t   = threadIdx.x;
    const int a   = t >> 5;         // full-stage: rows [8a, 8a+8)
    const int bb  = t & 31;         // full-stage: cols 4bb.. / 128+4bb..
    const int w   = t >> 6;         // wave 0..15
    const int l   = t & 63;
    const int g   = (t >> 4) & 3;   // k-group within wave
    const int l15 = t & 15;

    const int bat0 = blockIdx.x << 1;
    const int bat1 = bat0 + 1;
    const bool haveB1 = bat1 < B;

    const float alpha2 = alpha_p[0] * L2E;
    const float A  = fexp2(alpha2);
    const float Cs = fexp2(8.0f - alpha2);   // 2^8 / A
    const int iters = iters_p[0];

    __shared__ __align__(16) unsigned short esT[65536];  // 128 KB swizzled col-major
    __shared__ __align__(16) float rawbuf[4096];         // 16 KB raw-f32 staging
    __shared__ __align__(16) unsigned short EUa[272];
    __shared__ __align__(16) unsigned short EVa[272];
    __shared__ __align__(16) float wsU[16];
    __shared__ __align__(16) float wsV[16];

    float evd, eud_s;
    half8 esA[8], esB[8];

    // ---------------- full stage of bat0 (v11 prologue) ----------------
    {
        const float* sp = scores + ((size_t)bat0 << 16) + ((size_t)a << 11) + (bb << 2);
        half8 cp[8];
        #pragma unroll
        for (int r = 0; r < 8; ++r) {
            const float4 x0 = *reinterpret_cast<const float4*>(sp + (r << 8));
            const float4 x1 = *reinterpret_cast<const float4*>(sp + (r << 8) + 128);
            cp[0][r] = (_Float16)fexp2(x0.x * L2E);
            cp[1][r] = (_Float16)fexp2(x0.y * L2E);
            cp[2][r] = (_Float16)fexp2(x0.z * L2E);
            cp[3][r] = (_Float16)fexp2(x0.w * L2E);
            cp[4][r] = (_Float16)fexp2(x1.x * L2E);
            cp[5][r] = (_Float16)fexp2(x1.y * L2E);
            cp[6][r] = (_Float16)fexp2(x1.z * L2E);
            cp[7][r] = (_Float16)fexp2(x1.w * L2E);
        }
        #pragma unroll
        for (int ci = 0; ci < 8; ++ci) {
            const int col = (ci < 4) ? ((bb << 2) + ci) : (128 + (bb << 2) + ci - 4);
            const int idx = (col << 8) + (((a << 3)) ^ ((col & 7) << 3));
            *reinterpret_cast<half8*>(&esT[idx]) = cp[ci];
        }
    }
    if (t < 256) EVa[t] = 0x3C00;      // EV = 1.0 (f16)
    if (t < 16)  wsV[t] = 16.0f;       // per-wave sum of 16 ones
    __syncthreads();

    // ---- fragment gather from esT (asm-pinned; reused for both batches) ----
    auto gather = [&]() {
        const int m16 = (w << 4) + l15;
        #pragma unroll
        for (int s = 0; s < 8; ++s) {
            #pragma unroll
            for (int j = 0; j < 8; ++j) {
                const int col = (s << 5) + (g << 3) + j;
                esA[s][j] = __builtin_bit_cast(_Float16,
                    esT[(col << 8) + (m16 ^ ((col & 7) << 3))]);
            }
            asm volatile("" : "+v"(esA[s]));  // opaque def: no remat
        }
        const int cbase = ((w << 4) + l15) << 8;
        const int swq = (l15 & 7) << 3;
        #pragma unroll
        for (int s = 0; s < 8; ++s) {
            esB[s] = *reinterpret_cast<const half8*>(
                &esT[cbase + (((s << 5) + (g << 3)) ^ swq)]);
            asm volatile("" : "+v"(esB[s]));
        }
    };

    // ---- bat1 staging primitives (zero long-lived VGPRs) ----
    const float* sB1 = scores + ((size_t)bat1 << 16);
    auto issue_chunk = [&](int c) {   // wave w loads its private 1 KB of chunk c
        const float* gp = sB1 + (c << 12) + (w << 8) + (l << 2);
        __builtin_amdgcn_global_load_lds(
            (const __attribute__((address_space(1))) void*)gp,
            (__attribute__((address_space(3))) void*)&rawbuf[w << 8],
            16, 0, 0);
    };
    auto consume_chunk = [&](int c) {  // thread converts its own wave's 16 B
        const float4 v = *reinterpret_cast<const float4*>(&rawbuf[t << 2]);
        const int row   = (c << 4) + (t >> 6);
        const int cb    = (t & 63) << 2;
        const int rslot = row & ~7;
        const int rin   = row & 7;
        const float vv[4] = {v.x, v.y, v.z, v.w};
        #pragma unroll
        for (int cc = 0; cc < 4; ++cc) {
            const int col = cb + cc;
            esT[(col << 8) + ((rslot ^ ((col & 7) << 3)) + rin)] =
                __builtin_bit_cast(unsigned short, (_Float16)fexp2(vv[cc] * L2E));
        }
    };

    // ---- v9 loop body (verbatim), with optional staging hooks ----
    const half8* evp = reinterpret_cast<const half8*>(EVa) + g;
    const half8* eup = reinterpret_cast<const half8*>(EUa) + g;

    auto run_loop = [&](bool doStage) {
        evd = 1.0f; eud_s = 1.0f;
        for (int it = 0; it < iters; ++it) {
            if (doStage) {
                if (it >= 1 && it <= 16) {
                    asm volatile("s_waitcnt vmcnt(0)" ::: "memory");
                    consume_chunk(it - 1);
                }
                if (it <= 15) issue_chunk(it);
            }

            // ---- scalars: eud_s from Sum(EV) + evd (all threads, redundant) ----
            float sv = evd;
            {
                const floatx4* wv = reinterpret_cast<const floatx4*>(wsV);
                floatx4 s0 = wv[0], s1 = wv[1], s2 = wv[2], s3 = wv[3];
                floatx4 ss = (s0 + s1) + (s2 + s3);
                sv += (ss[0] + ss[1]) + (ss[2] + ss[3]);
            }
            eud_s = Cs * rcp_nr(sv);
            const float tdu = A * eud_s;
            const float tdv = A * evd;

            // ---- p-phase: D[m][*] = sum_k es[m][k]*EV[k] (2x4 chains) ----
            floatx4 acc0 = {0.f, 0.f, 0.f, 0.f}, acc1 = {0.f, 0.f, 0.f, 0.f};
            #pragma unroll
            for (int s = 0; s < 4; ++s) {
                acc0 = __builtin_amdgcn_mfma_f32_16x16x32_f16(esA[2*s],   evp[(2*s) << 2],   acc0, 0, 0, 0);
                acc1 = __builtin_amdgcn_mfma_f32_16x16x32_f16(esA[2*s+1], evp[(2*s+1) << 2], acc1, 0, 0, 0);
            }
            floatx4 acc = acc0 + acc1;

            const float E0 = rcp_nr(acc[0] + tdv);
            const float E1 = rcp_nr(acc[1] + tdv);
            const float E2 = rcp_nr(acc[2] + tdv);
            const float E3 = rcp_nr(acc[3] + tdv);
            if (l15 < 4) {  // rows 16w + 4g + l15
                const float lo  = (l15 & 1) ? E1 : E0;
                const float hi  = (l15 & 1) ? E3 : E2;
                const float val = (l15 & 2) ? hi : lo;
                EUa[(w << 4) + (g << 2) + l15] =
                    __builtin_bit_cast(unsigned short, (_Float16)val);
            }
            float sU = (E0 + E1) + (E2 + E3);
            sU = xor16_add(sU);
            sU += __shfl_xor(sU, 32, 64);
            if (l == 0) wsU[w] = sU;
            __syncthreads();

            // ---- scalars: evd' from Sum(EU) + eud_s ----
            float su = eud_s;
            {
                const floatx4* wu = reinterpret_cast<const floatx4*>(wsU);
                floatx4 s0 = wu[0], s1 = wu[1], s2 = wu[2], s3 = wu[3];
                floatx4 ss = (s0 + s1) + (s2 + s3);
                su += (ss[0] + ss[1]) + (ss[2] + ss[3]);
            }
            evd = Cs * rcp_nr(su);

            // ---- q-phase: D[*][n] = sum_k EU[k]*es[k][n] (2x4 chains) ----
            floatx4 q0 = {0.f, 0.f, 0.f, 0.f}, q1 = {0.f, 0.f, 0.f, 0.f};
            #pragma unroll
            for (int s = 0; s < 4; ++s) {
                q0 = __builtin_amdgcn_mfma_f32_16x16x32_f16(eup[(2*s) << 2],   esB[2*s],   q0, 0, 0, 0);
                q1 = __builtin_amdgcn_mfma_f32_16x16x32_f16(eup[(2*s+1) << 2], esB[2*s+1], q1, 0, 0, 0);
            }
            floatx4 acc2 = q0 + q1;

            const float EVv = rcp_nr(acc2[0] + tdu);   // col 16w+l15
            if (l < 16) EVa[(w << 4) + l] =
                __builtin_bit_cast(unsigned short, (_Float16)EVv);
            float sV = reduce16(EVv);
            if (l == 0) wsV[w] = sV;
            __syncthreads();
        }
    };

    // ---- epilogue from fragments (esT may hold the NEXT batch) ----
    auto do_epilogue = [&](int bat) {
        const float Ud = flog2(eud_s);
        const float Vd = flog2(evd);
        const float Up_l = flog2((float)__builtin_bit_cast(_Float16, EUa[(w << 4) + l15]));
        const int row = (w << 4) + l15;
        const size_t ob = (size_t)bat * 66049;  // 257*257
        float* rp = out + ob + (size_t)row * 257;
        #pragma unroll
        for (int s = 0; s < 8; ++s) {
            const half8 ev8 = evp[s << 2];   // per-s read: low reg pressure
            const int c0 = (s << 5) + (g << 3);
            #pragma unroll
            for (int j = 0; j < 8; ++j)
                rp[c0 + j] = (flog2((float)esA[s][j]) + Up_l + flog2((float)ev8[j])) * LN2;
        }
        if (l < 16) rp[256] = (alpha2 + Up_l + Vd) * LN2;   // dustbin column
        if (t < 257) {
            const float vp = (t < 256)
                ? flog2((float)__builtin_bit_cast(_Float16, EVa[t])) : Vd;
            out[ob + 65792 + t] = (alpha2 + Ud + vp) * LN2;
        }
    };

    // ================= batch 0 =================
    gather();
    run_loop(haveB1);
    if (haveB1) {
        // catch-up staging (no-op when iters >= 17)
        const int consumed = (iters >= 1) ? ((iters - 1) < 16 ? (iters - 1) : 16) : 0;
        const int issuedN  = (iters < 16) ? (iters < 0 ? 0 : iters) : 16;
        for (int c = consumed; c < 16; ++c) {
            if (c >= issuedN) issue_chunk(c);
            asm volatile("s_waitcnt vmcnt(0)" ::: "memory");
            consume_chunk(c);
        }
    }
    do_epilogue(bat0);

    if (!haveB1) return;

    // ================= batch 1 =================
    __syncthreads();                   // staging writes + epi reads drained
    if (t < 256) EVa[t] = 0x3C00;
    if (t < 16)  wsV[t] = 16.0f;
    gather();                          // esT now holds bat1
    __syncthreads();
    run_loop(false);
    do_epilogue(bat1);
}

extern "C" void kernel_launch(void* const* d_in, const int* in_sizes, int n_in,
                              void* d_out, int out_size, void* d_ws, size_t ws_size,
                              hipStream_t stream)
{
    const float* scores = (const float*)d_in[0];
    const float* alpha  = (const float*)d_in[1];
    const int*   iters  = (const int*)d_in[2];
    float* out = (float*)d_out;
    const int B = in_sizes[0] >> 16;
    hipLaunchKernelGGL(sinkhorn_kernel, dim3((B + 1) >> 1), dim3(1024), 0, stream,
                       scores, alpha, iters, out, B);
}

// Round 13
// 119.420 us; speedup vs baseline: 1.1382x; 1.1382x over previous
//
#include <hip/hip_runtime.h>

// Sinkhorn (dustbin-augmented), MFMA edition v13 = v12 double-batch pipeline
// with the LDS layout fixed:
//  * esT column stride 264 shorts (528 B): consecutive columns land on
//    different banks (132 dwords == 4 mod 32) -> kills v12's 64-way staging
//    write conflicts AND v9's 16-way esB-gather conflicts.
//  * staging consume writes ONE ds_write_b64 per thread (col-major 4
//    consecutive rows), instead of 4 scattered b16s.
//
// Scaled exp-domain state (A = 2^{alpha*log2e}, Cs = 2^8/A):
//   EU_i  = 1/(sum_j es_ij*EV_j + A*evd)         es = 2^{s*log2e} (f16)
//   eud_s = Cs/(sum_j EV_j + evd)
//   EV_j  = 1/(sum_i es_ij*EU_i + A*eud_s)
//   evd'  = Cs/(sum_i EU_i + eud_s)
//   Z core = (log2 es + log2 EU + log2 EV)*ln2   (dustbins use alpha2)
//
// Staging (batch k+1 during batch k's loop): chunk c = 16 rows (16 KB raw).
// Iter c: issue 1 global_load_lds_dwordx4/wave (wave-uniform LDS dest =
// rawbuf[w*1KB], per-lane global src). Iter c+1: vmcnt(0) (load is a full
// iteration old -> no stall), each thread converts its own wave's 4 floats
// (4 rows x 1 col) -> one b64 esT write. Wave-private rawbuf regions.
//
// Fragment maps (proven v8..v12): wave w, lane l = l15 + 16g:
//   esA[s][j] = es[16w+l15][s*32+g*8+j]   (A operand, row strip)
//   esB[s][j] = es[s*32+g*8+j][16w+l15]   (B operand, col strip)
// C/D layout: col=lane&15, row=(lane>>4)*4+reg (HW-measured).

typedef _Float16 half8 __attribute__((ext_vector_type(8)));
typedef _Float16 half4 __attribute__((ext_vector_type(4)));
typedef float floatx4 __attribute__((ext_vector_type(4)));

#define PSE 264  // esT column stride in shorts (16B-aligned, bank-spreading)

constexpr float L2E = 1.4426950408889634f;
constexpr float LN2 = 0.6931471805599453f;

__device__ __forceinline__ float flog2(float x) { return __builtin_amdgcn_logf(x); }
__device__ __forceinline__ float fexp2(float x) { return __builtin_amdgcn_exp2f(x); }

__device__ __forceinline__ float rcp_nr(float d) {
    float r = __builtin_amdgcn_rcpf(d);
    return r * fmaf(-d, r, 2.0f);
}

template <int CTRL>
__device__ __forceinline__ float dpp_add(float x) {
    int y = __builtin_amdgcn_update_dpp(0, __builtin_bit_cast(int, x), CTRL, 0xF, 0xF, true);
    return x + __builtin_bit_cast(float, y);
}
__device__ __forceinline__ float reduce16(float x) {
    x = dpp_add<0xB1>(x);    // xor 1
    x = dpp_add<0x4E>(x);    // xor 2
    x = dpp_add<0x124>(x);   // row_ror:4
    x = dpp_add<0x128>(x);   // row_ror:8
    return x;
}
__device__ __forceinline__ float xor16_add(float x) {
    int y = __builtin_amdgcn_ds_swizzle(__builtin_bit_cast(int, x), 0x401F);
    return x + __builtin_bit_cast(float, y);
}

__global__ __launch_bounds__(1024)
__attribute__((amdgpu_waves_per_eu(4, 4)))
void sinkhorn_kernel(const float* __restrict__ scores,
                     const float* __restrict__ alpha_p,
                     const int* __restrict__ iters_p,
                     float* __restrict__ out, int B)
{
    const int t   = threadIdx.x;
    const int a   = t >> 5;         // full-stage: rows [8a, 8a+8)
    const int bb  = t & 31;         // full-stage: cols 4bb.. / 128+4bb..
    const int w   = t >> 6;         // wave 0..15
    const int l   = t & 63;
    const int g   = (t >> 4) & 3;   // k-group within wave
    const int l15 = t & 15;

    const int bat0 = blockIdx.x << 1;
    const int bat1 = bat0 + 1;
    const bool haveB1 = bat1 < B;

    const float alpha2 = alpha_p[0] * L2E;
    const float A  = fexp2(alpha2);
    const float Cs = fexp2(8.0f - alpha2);   // 2^8 / A
    const int iters = iters_p[0];

    __shared__ __align__(16) unsigned short esT[256 * PSE];  // 132 KB swizzled col-major
    __shared__ __align__(16) float rawbuf[4096];             // 16 KB raw-f32 staging
    __shared__ __align__(16) unsigned short EUa[272];
    __shared__ __align__(16) unsigned short EVa[272];
    __shared__ __align__(16) float wsU[16];
    __shared__ __align__(16) float wsV[16];

    float evd, eud_s;
    half8 esA[8], esB[8];

    // ---------------- full stage of bat0 ----------------
    {
        const float* sp = scores + ((size_t)bat0 << 16) + ((size_t)a << 11) + (bb << 2);
        half8 cp[8];
        #pragma unroll
        for (int r = 0; r < 8; ++r) {
            const float4 x0 = *reinterpret_cast<const float4*>(sp + (r << 8));
            const float4 x1 = *reinterpret_cast<const float4*>(sp + (r << 8) + 128);
            cp[0][r] = (_Float16)fexp2(x0.x * L2E);
            cp[1][r] = (_Float16)fexp2(x0.y * L2E);
            cp[2][r] = (_Float16)fexp2(x0.z * L2E);
            cp[3][r] = (_Float16)fexp2(x0.w * L2E);
            cp[4][r] = (_Float16)fexp2(x1.x * L2E);
            cp[5][r] = (_Float16)fexp2(x1.y * L2E);
            cp[6][r] = (_Float16)fexp2(x1.z * L2E);
            cp[7][r] = (_Float16)fexp2(x1.w * L2E);
        }
        #pragma unroll
        for (int ci = 0; ci < 8; ++ci) {
            const int col = (ci < 4) ? ((bb << 2) + ci) : (128 + (bb << 2) + ci - 4);
            const int idx = col * PSE + (((a << 3)) ^ ((col & 7) << 3));
            *reinterpret_cast<half8*>(&esT[idx]) = cp[ci];
        }
    }
    if (t < 256) EVa[t] = 0x3C00;      // EV = 1.0 (f16)
    if (t < 16)  wsV[t] = 16.0f;       // per-wave sum of 16 ones
    __syncthreads();

    // ---- fragment gather from esT (asm-pinned) ----
    auto gather = [&]() {
        const int m16 = (w << 4) + l15;
        #pragma unroll
        for (int s = 0; s < 8; ++s) {
            #pragma unroll
            for (int j = 0; j < 8; ++j) {
                const int col = (s << 5) + (g << 3) + j;
                esA[s][j] = __builtin_bit_cast(_Float16,
                    esT[col * PSE + (m16 ^ ((col & 7) << 3))]);
            }
            asm volatile("" : "+v"(esA[s]));  // opaque def: no remat
        }
        const int cbase = ((w << 4) + l15) * PSE;
        const int swq = (l15 & 7) << 3;
        #pragma unroll
        for (int s = 0; s < 8; ++s) {
            esB[s] = *reinterpret_cast<const half8*>(
                &esT[cbase + (((s << 5) + (g << 3)) ^ swq)]);
            asm volatile("" : "+v"(esB[s]));
        }
    };

    // ---- bat1 staging primitives (zero long-lived VGPRs) ----
    const float* sB1 = scores + ((size_t)bat1 << 16);
    // wave w, chunk c: rows [16c+4(w>>2), +4), cols [64(w&3), +64)
    auto issue_chunk = [&](int c) {
        const int row = (c << 4) + ((w >> 2) << 2) + (l >> 4);
        const int col = ((w & 3) << 6) + ((l & 15) << 2);
        const float* gp = sB1 + (row << 8) + col;
        __builtin_amdgcn_global_load_lds(
            (const __attribute__((address_space(1))) void*)gp,
            (__attribute__((address_space(3))) void*)&rawbuf[w << 8],
            16, 0, 0);   // lane l lands at rawbuf[w*256 + l*4]
    };
    auto consume_chunk = [&](int c) {
        // thread: col = 64(w&3)+l, rows 16c+4(w>>2)+k (k=0..3), own wave region
        const int col = ((w & 3) << 6) + l;
        const int r0  = (c << 4) + ((w >> 2) << 2);
        float v[4];
        #pragma unroll
        for (int k = 0; k < 4; ++k)
            v[k] = rawbuf[(w << 8) + (k << 6) + ((l >> 2) << 2) + (l & 3)];
        half4 h;
        #pragma unroll
        for (int k = 0; k < 4; ++k) h[k] = (_Float16)fexp2(v[k] * L2E);
        const int rslot = r0 & ~7;
        const int rin   = r0 & 7;
        *reinterpret_cast<half4*>(
            &esT[col * PSE + (rslot ^ ((col & 7) << 3)) + rin]) = h;
    };

    // ---- v9 loop body (verbatim), with staging hooks ----
    const half8* evp = reinterpret_cast<const half8*>(EVa) + g;
    const half8* eup = reinterpret_cast<const half8*>(EUa) + g;

    auto run_loop = [&](bool doStage) {
        evd = 1.0f; eud_s = 1.0f;
        for (int it = 0; it < iters; ++it) {
            if (doStage) {
                if (it >= 1 && it <= 16) {
                    asm volatile("s_waitcnt vmcnt(0)" ::: "memory");
                    consume_chunk(it - 1);
                }
                if (it <= 15) issue_chunk(it);
            }

            // ---- scalars: eud_s from Sum(EV) + evd ----
            float sv = evd;
            {
                const floatx4* wv = reinterpret_cast<const floatx4*>(wsV);
                floatx4 s0 = wv[0], s1 = wv[1], s2 = wv[2], s3 = wv[3];
                floatx4 ss = (s0 + s1) + (s2 + s3);
                sv += (ss[0] + ss[1]) + (ss[2] + ss[3]);
            }
            eud_s = Cs * rcp_nr(sv);
            const float tdu = A * eud_s;
            const float tdv = A * evd;

            // ---- p-phase: D[m][*] = sum_k es[m][k]*EV[k] (2x4 chains) ----
            floatx4 acc0 = {0.f, 0.f, 0.f, 0.f}, acc1 = {0.f, 0.f, 0.f, 0.f};
            #pragma unroll
            for (int s = 0; s < 4; ++s) {
                acc0 = __builtin_amdgcn_mfma_f32_16x16x32_f16(esA[2*s],   evp[(2*s) << 2],   acc0, 0, 0, 0);
                acc1 = __builtin_amdgcn_mfma_f32_16x16x32_f16(esA[2*s+1], evp[(2*s+1) << 2], acc1, 0, 0, 0);
            }
            floatx4 acc = acc0 + acc1;

            const float E0 = rcp_nr(acc[0] + tdv);
            const float E1 = rcp_nr(acc[1] + tdv);
            const float E2 = rcp_nr(acc[2] + tdv);
            const float E3 = rcp_nr(acc[3] + tdv);
            if (l15 < 4) {  // rows 16w + 4g + l15
                const float lo  = (l15 & 1) ? E1 : E0;
                const float hi  = (l15 & 1) ? E3 : E2;
                const float val = (l15 & 2) ? hi : lo;
                EUa[(w << 4) + (g << 2) + l15] =
                    __builtin_bit_cast(unsigned short, (_Float16)val);
            }
            float sU = (E0 + E1) + (E2 + E3);
            sU = xor16_add(sU);
            sU += __shfl_xor(sU, 32, 64);
            if (l == 0) wsU[w] = sU;
            __syncthreads();

            // ---- scalars: evd' from Sum(EU) + eud_s ----
            float su = eud_s;
            {
                const floatx4* wu = reinterpret_cast<const floatx4*>(wsU);
                floatx4 s0 = wu[0], s1 = wu[1], s2 = wu[2], s3 = wu[3];
                floatx4 ss = (s0 + s1) + (s2 + s3);
                su += (ss[0] + ss[1]) + (ss[2] + ss[3]);
            }
            evd = Cs * rcp_nr(su);

            // ---- q-phase: D[*][n] = sum_k EU[k]*es[k][n] (2x4 chains) ----
            floatx4 q0 = {0.f, 0.f, 0.f, 0.f}, q1 = {0.f, 0.f, 0.f, 0.f};
            #pragma unroll
            for (int s = 0; s < 4; ++s) {
                q0 = __builtin_amdgcn_mfma_f32_16x16x32_f16(eup[(2*s) << 2],   esB[2*s],   q0, 0, 0, 0);
                q1 = __builtin_amdgcn_mfma_f32_16x16x32_f16(eup[(2*s+1) << 2], esB[2*s+1], q1, 0, 0, 0);
            }
            floatx4 acc2 = q0 + q1;

            const float EVv = rcp_nr(acc2[0] + tdu);   // col 16w+l15
            if (l < 16) EVa[(w << 4) + l] =
                __builtin_bit_cast(unsigned short, (_Float16)EVv);
            float sV = reduce16(EVv);
            if (l == 0) wsV[w] = sV;
            __syncthreads();
        }
    };

    // ---- epilogue from fragments (esT may hold the NEXT batch) ----
    auto do_epilogue = [&](int bat) {
        const float Ud = flog2(eud_s);
        const float Vd = flog2(evd);
        const float Up_l = flog2((float)__builtin_bit_cast(_Float16, EUa[(w << 4) + l15]));
        const int row = (w << 4) + l15;
        const size_t ob = (size_t)bat * 66049;  // 257*257
        float* rp = out + ob + (size_t)row * 257;
        #pragma unroll
        for (int s = 0; s < 8; ++s) {
            const half8 ev8 = evp[s << 2];
            const int c0 = (s << 5) + (g << 3);
            #pragma unroll
            for (int j = 0; j < 8; ++j)
                rp[c0 + j] = (flog2((float)esA[s][j]) + Up_l + flog2((float)ev8[j])) * LN2;
        }
        if (l < 16) rp[256] = (alpha2 + Up_l + Vd) * LN2;   // dustbin column
        if (t < 257) {
            const float vp = (t < 256)
                ? flog2((float)__builtin_bit_cast(_Float16, EVa[t])) : Vd;
            out[ob + 65792 + t] = (alpha2 + Ud + vp) * LN2;
        }
    };

    // ================= batch 0 =================
    gather();
    run_loop(haveB1);
    if (haveB1) {
        // catch-up staging (no-op when iters >= 17)
        const int consumed = (iters >= 1) ? ((iters - 1) < 16 ? (iters - 1) : 16) : 0;
        const int issuedN  = (iters < 16) ? (iters < 0 ? 0 : iters) : 16;
        for (int c = consumed; c < 16; ++c) {
            if (c >= issuedN) issue_chunk(c);
            asm volatile("s_waitcnt vmcnt(0)" ::: "memory");
            consume_chunk(c);
        }
    }
    do_epilogue(bat0);

    if (!haveB1) return;

    // ================= batch 1 =================
    __syncthreads();                   // epi-0 reads of EVa/EUa drained
    if (t < 256) EVa[t] = 0x3C00;
    if (t < 16)  wsV[t] = 16.0f;
    gather();                          // esT holds bat1 (staged during loop 0)
    __syncthreads();
    run_loop(false);
    do_epilogue(bat1);
}

extern "C" void kernel_launch(void* const* d_in, const int* in_sizes, int n_in,
                              void* d_out, int out_size, void* d_ws, size_t ws_size,
                              hipStream_t stream)
{
    const float* scores = (const float*)d_in[0];
    const float* alpha  = (const float*)d_in[1];
    const int*   iters  = (const int*)d_in[2];
    float* out = (float*)d_out;
    const int B = in_sizes[0] >> 16;
    hipLaunchKernelGGL(sinkhorn_kernel, dim3((B + 1) >> 1), dim3(1024), 0, stream,
                       scores, alpha, iters, out, B);
}